// Round 10
// baseline (632.248 us; speedup 1.0000x reference)
//
#include <hip/hip_runtime.h>
#include <stdint.h>

#define AS1 __attribute__((address_space(1)))
#define AS3 __attribute__((address_space(3)))

typedef __attribute__((ext_vector_type(8))) short short8;
typedef __attribute__((ext_vector_type(4))) float floatx4;

__device__ __forceinline__ unsigned short f2b_rne(float f) {
  union { float f; unsigned u; } c; c.f = f;
  unsigned u = c.u;
  unsigned r = u + 0x7fffu + ((u >> 16) & 1u);
  return (unsigned short)(r >> 16);
}

__device__ __forceinline__ short8 cvt8(float4 a, float4 b) {
  union { short8 s; unsigned u[4]; } r;
  r.u[0] = ((unsigned)f2b_rne(a.y) << 16) | f2b_rne(a.x);
  r.u[1] = ((unsigned)f2b_rne(a.w) << 16) | f2b_rne(a.z);
  r.u[2] = ((unsigned)f2b_rne(b.y) << 16) | f2b_rne(b.x);
  r.u[3] = ((unsigned)f2b_rne(b.w) << 16) | f2b_rne(b.z);
  return r.s;
}

// ---------------------------------------------------------------------------
// One-shot fp32 -> bf16 (row-major, coalesced 16B/lane), grid-stride.
// Removes the per-k-step A conversion (VGPR round-trip + ~180cy VALU) from
// ALL 8 nt-blocks that restage each panel, and halves gemm A-fetch bytes.
// ---------------------------------------------------------------------------
__global__ __launch_bounds__(256)
void conv_bf16(const float* __restrict__ src, unsigned short* __restrict__ dst, int n8) {
  int i = blockIdx.x * 256 + threadIdx.x;
  const int stride = gridDim.x * 256;
  for (; i < n8; i += stride) {
    const float* g = src + (size_t)i * 8;
    float4 x0 = *(const float4*)g;
    float4 x1 = *(const float4*)(g + 4);
    *(short8*)(dst + (size_t)i * 8) = cvt8(x0, x1);
  }
}

// ---------------------------------------------------------------------------
// Weight prep: Wt[n][k] = bf16(W_seg[k][c])  (B^T layout, K contiguous)
// rows 0..255=W_val, 256..511=W_so, 512..767=W_tso.
// rows 768..1023: head-interleaved aw layout — idx=n-768, h=idx>>5, w=idx&31:
// w<16 -> W_aw col h*16+w ; w>=16 -> W_taw col h*16+(w-16). Each head's 32
// joint-softmax logits are one contiguous 32-col group -> 16-lane shfl softmax.
// ---------------------------------------------------------------------------
__global__ void prep_weights(const float* __restrict__ Wv,  const float* __restrict__ bv,
                             const float* __restrict__ Wso, const float* __restrict__ bso,
                             const float* __restrict__ Waw, const float* __restrict__ baw,
                             const float* __restrict__ Wtso,const float* __restrict__ btso,
                             const float* __restrict__ Wtaw,const float* __restrict__ btaw,
                             unsigned short* __restrict__ Wt, float* __restrict__ bcat) {
  int n = blockIdx.x;   // 0..1023
  int k = threadIdx.x;  // 0..255
  const float* W; const float* b; int c, N;
  if (n < 256)      { W = Wv;   b = bv;   c = n;       N = 256; }
  else if (n < 512) { W = Wso;  b = bso;  c = n - 256; N = 256; }
  else if (n < 768) { W = Wtso; b = btso; c = n - 512; N = 256; }
  else {
    int idx = n - 768, h = idx >> 5, w = idx & 31;
    if (w < 16) { W = Waw;  b = baw;  c = h * 16 + w;        N = 128; }
    else        { W = Wtaw; b = btaw; c = h * 16 + (w - 16); N = 128; }
  }
  Wt[n * 256 + k] = f2b_rne(W[(size_t)k * N + c]);
  if (k == 0) bcat[n] = b[c];
}

// ---------------------------------------------------------------------------
// Main GEMM — R6/R9 structure (best: 596.1), with A-staging switched from
// {fp32 load -> wait -> pack -> ds_write} to the SAME fire-and-forget
// global_load_lds DMA pattern as B (BF16A=true; fp32 path kept as the
// workspace fallback). k-loop has zero staging VALU and zero mid-step VMEM
// waits: issue 8 DMAs, barrier (drain), ds_read, MFMA.
// 128x128 tile, BK=64, grid (8, M/128), XCD-aware bijective remap (nwg=8*765)
// placing the 8 co-panel nt-blocks on ONE XCD (panel lives in that L2).
//   nt 0..1 value | 2..3 so | 4..5 tso | 6..7 aw + fused shfl softmax.
// ---------------------------------------------------------------------------
template <bool BF16A>
__global__ __launch_bounds__(256, 3)
void gemm_main(const float* __restrict__ Qf32, const float* __restrict__ Xf32,
               const unsigned short* __restrict__ Qbf, const unsigned short* __restrict__ Xbf,
               const unsigned short* __restrict__ Wt, const float* __restrict__ bcat,
               float* __restrict__ out, int M) {
  __shared__ __align__(16) unsigned short As[128 * 64];  // 16 KB
  __shared__ __align__(16) unsigned short Bs[128 * 64];  // 16 KB

  // ---- XCD-locality remap (bijective: gridDim = (8, 765)) ----
  const int id = blockIdx.x + 8 * blockIdx.y;
  const int w  = (id & 7) * gridDim.y + (id >> 3);
  const int nt = w & 7;
  const int mt = w >> 3;

  const int mBase = mt * 128;
  const int nBase = nt * 128;
  const float* A32          = (nt < 2) ? Xf32 : Qf32;
  const unsigned short* A16 = (nt < 2) ? Xbf  : Qbf;

  const int tid  = threadIdx.x;
  const int lane = tid & 63;
  const int wid  = tid >> 6;
  const int mw   = (wid >> 1) * 64;
  const int nw   = (wid & 1) * 64;
  const int lrow = lane & 15;
  const int quad = lane >> 4;

  floatx4 acc[4][4] = {};

  const float* Ab32          = A32 + (size_t)mBase * 256;
  const unsigned short* Ab16 = A16 + (size_t)mBase * 256;
  const unsigned short* Bb   = Wt  + (size_t)nBase * 256;

  for (int s = 0; s < 4; ++s) {
    const int k0 = s * 64;
    __syncthreads();
    // ---- B stage: 128x64 bf16 = 1024 x 16B chunks, 4/thread.
    // Fire-and-forget DMA; LDS dest linear, global source pre-swizzled.
#pragma unroll
    for (int j = 0; j < 4; ++j) {
      int ch = j * 256 + tid;
      int r = ch >> 3, kc = ch & 7;
      const unsigned short* g = Bb + (size_t)r * 256 + k0 + ((kc ^ (r & 7)) << 3);
      unsigned ldsoff = (unsigned)((j * 256 + (tid & ~63)) * 16);
      __builtin_amdgcn_global_load_lds((const AS1 void*)g,
                                       (AS3 void*)(((char*)Bs) + ldsoff), 16, 0, 0);
    }
    if constexpr (BF16A) {
      // ---- A stage: identical DMA pattern on the pre-converted bf16 A ----
#pragma unroll
      for (int j = 0; j < 4; ++j) {
        int ch = j * 256 + tid;
        int r = ch >> 3, kc = ch & 7;
        const unsigned short* g = Ab16 + (size_t)r * 256 + k0 + ((kc ^ (r & 7)) << 3);
        unsigned ldsoff = (unsigned)((j * 256 + (tid & ~63)) * 16);
        __builtin_amdgcn_global_load_lds((const AS1 void*)g,
                                         (AS3 void*)(((char*)As) + ldsoff), 16, 0, 0);
      }
    } else {
      // ---- fallback A stage: fp32 -> bf16 in-kernel (R9-verified) ----
      float4 va[8];
#pragma unroll
      for (int i = 0; i < 8; ++i) {
        int id2 = i * 256 + tid;
        int r = id2 >> 4, kc4 = id2 & 15;
        va[i] = *(const float4*)(Ab32 + (size_t)r * 256 + k0 + kc4 * 4);
      }
#pragma unroll
      for (int i = 0; i < 8; ++i) {
        int id2 = i * 256 + tid;
        int r = id2 >> 4, kc4 = id2 & 15;
        uint2 pk;
        pk.x = ((unsigned)f2b_rne(va[i].y) << 16) | f2b_rne(va[i].x);
        pk.y = ((unsigned)f2b_rne(va[i].w) << 16) | f2b_rne(va[i].z);
        int idx = r * 64 + ((((kc4 >> 1) ^ (r & 7)) << 3) + (kc4 & 1) * 4);
        *(uint2*)&As[idx] = pk;
      }
    }
    __syncthreads();
    // ---- compute: wave does 64x64 = 4x4 of 16x16x32, two k-halves ----
    short8 af[2][4], bf[2][4];
#pragma unroll
    for (int t = 0; t < 2; ++t) {
#pragma unroll
      for (int mi = 0; mi < 4; ++mi) {
        int row = mw + mi * 16 + lrow;
        af[t][mi] = *(const short8*)&As[row * 64 + (((t * 4 + quad) ^ (row & 7)) << 3)];
      }
#pragma unroll
      for (int ni = 0; ni < 4; ++ni) {
        int row = nw + ni * 16 + lrow;
        bf[t][ni] = *(const short8*)&Bs[row * 64 + (((t * 4 + quad) ^ (row & 7)) << 3)];
      }
    }
#pragma unroll
    for (int t = 0; t < 2; ++t)
#pragma unroll
      for (int mi = 0; mi < 4; ++mi)
#pragma unroll
        for (int ni = 0; ni < 4; ++ni)
          acc[mi][ni] = __builtin_amdgcn_mfma_f32_16x16x32_bf16(af[t][mi], bf[t][ni], acc[mi][ni], 0, 0, 0);
  }

  // C/D layout: col = lane&15, row = quad*4 + reg (m89-verified)
  if (nt < 6) {
    const int seg  = nt >> 1;
    const int half = nt & 1;
    float* Oseg = out + (size_t)seg * ((size_t)M * 256) + (size_t)half * 128;
    float bias[4];
#pragma unroll
    for (int ni = 0; ni < 4; ++ni) bias[ni] = bcat[nBase + nw + ni * 16 + lrow];
#pragma unroll
    for (int mi = 0; mi < 4; ++mi) {
#pragma unroll
      for (int r = 0; r < 4; ++r) {
        int row = mBase + mw + mi * 16 + quad * 4 + r;
#pragma unroll
        for (int ni = 0; ni < 4; ++ni) {
          int col = nw + ni * 16 + lrow;
          Oseg[(size_t)row * 256 + col] = acc[mi][ni][r] + bias[ni];
        }
      }
    }
  } else {
    // ---- aw: joint softmax over 32 logits per (row, head); wave = 2 heads.
    float* awc = out + (size_t)3 * ((size_t)M * 256);
    float* awt = awc + (size_t)M * 128;
    float bias[4];
#pragma unroll
    for (int ni = 0; ni < 4; ++ni) bias[ni] = bcat[nBase + nw + ni * 16 + lrow];
    const int hbase = ((nt - 6) * 128 + nw) >> 5;
#pragma unroll
    for (int mi = 0; mi < 4; ++mi) {
#pragma unroll
      for (int r = 0; r < 4; ++r) {
        const int row = mBase + mw + mi * 16 + quad * 4 + r;
#pragma unroll
        for (int hg = 0; hg < 2; ++hg) {
          float a = acc[mi][2 * hg + 0][r] + bias[2 * hg + 0];   // caw logit
          float b = acc[mi][2 * hg + 1][r] + bias[2 * hg + 1];   // taw logit
          float mx = fmaxf(a, b);
          mx = fmaxf(mx, __shfl_xor(mx, 1));
          mx = fmaxf(mx, __shfl_xor(mx, 2));
          mx = fmaxf(mx, __shfl_xor(mx, 4));
          mx = fmaxf(mx, __shfl_xor(mx, 8));
          float ea = __expf(a - mx), eb = __expf(b - mx);
          float ssum = ea + eb;
          ssum += __shfl_xor(ssum, 1);
          ssum += __shfl_xor(ssum, 2);
          ssum += __shfl_xor(ssum, 4);
          ssum += __shfl_xor(ssum, 8);
          float inv = 1.0f / ssum;
          const int h = hbase + hg;
          awc[(size_t)row * 128 + h * 16 + lrow] = ea * inv;
          awt[(size_t)row * 128 + h * 16 + lrow] = eb * inv;
        }
      }
    }
  }
}

// ---------------------------------------------------------------------------
extern "C" void kernel_launch(void* const* d_in, const int* in_sizes, int n_in,
                              void* d_out, int out_size, void* d_ws, size_t ws_size,
                              hipStream_t stream) {
  const float* Q    = (const float*)d_in[0];
  const float* Xf32 = (const float*)d_in[1];
  const float* Wv   = (const float*)d_in[2];
  const float* bv   = (const float*)d_in[3];
  const float* Wso  = (const float*)d_in[4];
  const float* bso  = (const float*)d_in[5];
  const float* Waw  = (const float*)d_in[6];
  const float* baw  = (const float*)d_in[7];
  const float* Wtso = (const float*)d_in[8];
  const float* btso = (const float*)d_in[9];
  const float* Wtaw = (const float*)d_in[10];
  const float* btaw = (const float*)d_in[11];
  float* out = (float*)d_out;

  int M = in_sizes[0] / 256;  // 97920

  unsigned short* Wt = (unsigned short*)d_ws;               // 512 KB
  float* bcat = (float*)((char*)d_ws + 1024 * 256 * 2);     // 4 KB
  size_t abytes = (size_t)M * 256 * 2;                      // 50.1 MB each
  size_t need = 1024 * 256 * 2 + 4096 + 2 * abytes;

  prep_weights<<<1024, 256, 0, stream>>>(Wv, bv, Wso, bso, Waw, baw,
                                         Wtso, btso, Wtaw, btaw, Wt, bcat);

  dim3 g(8, M / 128);  // remapped in-kernel for XCD L2 panel locality
  if (ws_size >= need) {
    unsigned short* Qbf = (unsigned short*)((char*)d_ws + 1024 * 256 * 2 + 4096);
    unsigned short* Xbf = (unsigned short*)((char*)Qbf + abytes);
    int n8 = M * 32;   // 8-element chunks per matrix
    conv_bf16<<<2048, 256, 0, stream>>>(Q, Qbf, n8);
    conv_bf16<<<2048, 256, 0, stream>>>(Xf32, Xbf, n8);
    gemm_main<true><<<g, 256, 0, stream>>>(Q, Xf32, Qbf, Xbf, Wt, bcat, out, M);
  } else {
    gemm_main<false><<<g, 256, 0, stream>>>(Q, Xf32, nullptr, nullptr, Wt, bcat, out, M);
  }
}

// Round 11
// 593.038 us; speedup vs baseline: 1.0661x; 1.0661x over previous
//
#include <hip/hip_runtime.h>
#include <stdint.h>

#define AS1 __attribute__((address_space(1)))
#define AS3 __attribute__((address_space(3)))

typedef __attribute__((ext_vector_type(8))) short short8;
typedef __attribute__((ext_vector_type(4))) float floatx4;

__device__ __forceinline__ unsigned short f2b_rne(float f) {
  union { float f; unsigned u; } c; c.f = f;
  unsigned u = c.u;
  unsigned r = u + 0x7fffu + ((u >> 16) & 1u);
  return (unsigned short)(r >> 16);
}

// ---------------------------------------------------------------------------
// Weight prep: Wt[n][k] = bf16(W_seg[k][c])  (B^T layout, K contiguous)
// rows 0..255=W_val, 256..511=W_so, 512..767=W_tso.
// rows 768..1023: head-interleaved aw layout — idx=n-768, h=idx>>5, w=idx&31:
// w<16 -> W_aw col h*16+w ; w>=16 -> W_taw col h*16+(w-16). Each head's 32
// joint-softmax logits are one contiguous 32-col group -> 16-lane shfl softmax.
// ---------------------------------------------------------------------------
__global__ void prep_weights(const float* __restrict__ Wv,  const float* __restrict__ bv,
                             const float* __restrict__ Wso, const float* __restrict__ bso,
                             const float* __restrict__ Waw, const float* __restrict__ baw,
                             const float* __restrict__ Wtso,const float* __restrict__ btso,
                             const float* __restrict__ Wtaw,const float* __restrict__ btaw,
                             unsigned short* __restrict__ Wt, float* __restrict__ bcat) {
  int n = blockIdx.x;   // 0..1023
  int k = threadIdx.x;  // 0..255
  const float* W; const float* b; int c, N;
  if (n < 256)      { W = Wv;   b = bv;   c = n;       N = 256; }
  else if (n < 512) { W = Wso;  b = bso;  c = n - 256; N = 256; }
  else if (n < 768) { W = Wtso; b = btso; c = n - 512; N = 256; }
  else {
    int idx = n - 768, h = idx >> 5, w = idx & 31;
    if (w < 16) { W = Waw;  b = baw;  c = h * 16 + w;        N = 128; }
    else        { W = Wtaw; b = btaw; c = h * 16 + (w - 16); N = 128; }
  }
  Wt[n * 256 + k] = f2b_rne(W[(size_t)k * N + c]);
  if (k == 0) bcat[n] = b[c];
}

// ---------------------------------------------------------------------------
// Main GEMM — best verified configuration (596.1 µs total, R9).
// 128x128 tile, BK=64, grid (8, M/128), XCD-aware bijective remap (nwg=8*765)
// placing the 8 co-panel nt-blocks on ONE XCD (panel lives in that L2 — the
// one lever that measurably helped: -27 µs vs linear dispatch).
//   nt 0..1 value | 2..3 so | 4..5 tso | 6..7 aw + fused shfl softmax.
// B staged via global_load_lds (linear dest, pre-swizzled source); A staged
// fp32->bf16 in-kernel with all 8 float4 loads issued before any pack (full
// MLP; splitting this was the R8 regression). Fragment reads 16B-XOR
// swizzled (2-way banks = free). Epilogue stores row-major. Tested-neutral:
// barrier halving, dbuf pipelining, bf16-A pre-pass, occupancy 4/CU, 256-col
// tiles. Tested-negative: no-LDS register GEMM, A-load splitting.
// ---------------------------------------------------------------------------
__global__ __launch_bounds__(256, 3)
void gemm_main(const float* __restrict__ Q, const float* __restrict__ X,
               const unsigned short* __restrict__ Wt, const float* __restrict__ bcat,
               float* __restrict__ out, int M) {
  __shared__ __align__(16) unsigned short As[128 * 64];  // 16 KB
  __shared__ __align__(16) unsigned short Bs[128 * 64];  // 16 KB

  // ---- XCD-locality remap (bijective: gridDim = (8, 765)) ----
  const int id = blockIdx.x + 8 * blockIdx.y;
  const int w  = (id & 7) * gridDim.y + (id >> 3);
  const int nt = w & 7;
  const int mt = w >> 3;

  const int mBase = mt * 128;
  const int nBase = nt * 128;
  const float* A = (nt < 2) ? X : Q;

  const int tid  = threadIdx.x;
  const int lane = tid & 63;
  const int wid  = tid >> 6;
  const int mw   = (wid >> 1) * 64;
  const int nw   = (wid & 1) * 64;
  const int lrow = lane & 15;
  const int quad = lane >> 4;

  floatx4 acc[4][4] = {};

  const float* Ab = A + (size_t)mBase * 256;
  const unsigned short* Bb = Wt + (size_t)nBase * 256;

  for (int s = 0; s < 4; ++s) {
    const int k0 = s * 64;
    __syncthreads();
    // ---- B stage: 128x64 bf16 = 1024 x 16B chunks, 4/thread.
    // Fire-and-forget DMA; LDS dest linear, global source pre-swizzled.
#pragma unroll
    for (int j = 0; j < 4; ++j) {
      int ch = j * 256 + tid;
      int r = ch >> 3, kc = ch & 7;
      const unsigned short* g = Bb + (size_t)r * 256 + k0 + ((kc ^ (r & 7)) << 3);
      unsigned ldsoff = (unsigned)((j * 256 + (tid & ~63)) * 16);
      __builtin_amdgcn_global_load_lds((const AS1 void*)g,
                                       (AS3 void*)(((char*)Bs) + ldsoff), 16, 0, 0);
    }
    // ---- A stage: 128x64 fp32 -> bf16: 8 float4/thread, ALL loads issued
    // before any pack (full MLP — the R8 split was the regression). ----
    float4 va[8];
#pragma unroll
    for (int i = 0; i < 8; ++i) {
      int id2 = i * 256 + tid;
      int r = id2 >> 4, kc4 = id2 & 15;
      va[i] = *(const float4*)(Ab + (size_t)r * 256 + k0 + kc4 * 4);
    }
#pragma unroll
    for (int i = 0; i < 8; ++i) {
      int id2 = i * 256 + tid;
      int r = id2 >> 4, kc4 = id2 & 15;
      uint2 pk;
      pk.x = ((unsigned)f2b_rne(va[i].y) << 16) | f2b_rne(va[i].x);
      pk.y = ((unsigned)f2b_rne(va[i].w) << 16) | f2b_rne(va[i].z);
      int idx = r * 64 + ((((kc4 >> 1) ^ (r & 7)) << 3) + (kc4 & 1) * 4);
      *(uint2*)&As[idx] = pk;
    }
    __syncthreads();
    // ---- compute: wave does 64x64 = 4x4 of 16x16x32, two k-halves ----
    short8 af[2][4], bf[2][4];
#pragma unroll
    for (int t = 0; t < 2; ++t) {
#pragma unroll
      for (int mi = 0; mi < 4; ++mi) {
        int row = mw + mi * 16 + lrow;
        af[t][mi] = *(const short8*)&As[row * 64 + (((t * 4 + quad) ^ (row & 7)) << 3)];
      }
#pragma unroll
      for (int ni = 0; ni < 4; ++ni) {
        int row = nw + ni * 16 + lrow;
        bf[t][ni] = *(const short8*)&Bs[row * 64 + (((t * 4 + quad) ^ (row & 7)) << 3)];
      }
    }
#pragma unroll
    for (int t = 0; t < 2; ++t)
#pragma unroll
      for (int mi = 0; mi < 4; ++mi)
#pragma unroll
        for (int ni = 0; ni < 4; ++ni)
          acc[mi][ni] = __builtin_amdgcn_mfma_f32_16x16x32_bf16(af[t][mi], bf[t][ni], acc[mi][ni], 0, 0, 0);
  }

  // C/D layout: col = lane&15, row = quad*4 + reg (m89-verified)
  if (nt < 6) {
    const int seg  = nt >> 1;
    const int half = nt & 1;
    float* Oseg = out + (size_t)seg * ((size_t)M * 256) + (size_t)half * 128;
    float bias[4];
#pragma unroll
    for (int ni = 0; ni < 4; ++ni) bias[ni] = bcat[nBase + nw + ni * 16 + lrow];
    // row-major issue order: per row, the 4 x 64-B col segments go out
    // back-to-back so their 128-B L2 lines complete immediately.
#pragma unroll
    for (int mi = 0; mi < 4; ++mi) {
#pragma unroll
      for (int r = 0; r < 4; ++r) {
        int row = mBase + mw + mi * 16 + quad * 4 + r;
#pragma unroll
        for (int ni = 0; ni < 4; ++ni) {
          int col = nw + ni * 16 + lrow;
          Oseg[(size_t)row * 256 + col] = acc[mi][ni][r] + bias[ni];
        }
      }
    }
  } else {
    // ---- aw: joint softmax over 32 logits per (row, head); wave = 2 heads.
    float* awc = out + (size_t)3 * ((size_t)M * 256);
    float* awt = awc + (size_t)M * 128;
    float bias[4];
#pragma unroll
    for (int ni = 0; ni < 4; ++ni) bias[ni] = bcat[nBase + nw + ni * 16 + lrow];
    const int hbase = ((nt - 6) * 128 + nw) >> 5;
#pragma unroll
    for (int mi = 0; mi < 4; ++mi) {
#pragma unroll
      for (int r = 0; r < 4; ++r) {
        const int row = mBase + mw + mi * 16 + quad * 4 + r;
#pragma unroll
        for (int hg = 0; hg < 2; ++hg) {
          float a = acc[mi][2 * hg + 0][r] + bias[2 * hg + 0];   // caw logit
          float b = acc[mi][2 * hg + 1][r] + bias[2 * hg + 1];   // taw logit
          float mx = fmaxf(a, b);
          mx = fmaxf(mx, __shfl_xor(mx, 1));
          mx = fmaxf(mx, __shfl_xor(mx, 2));
          mx = fmaxf(mx, __shfl_xor(mx, 4));
          mx = fmaxf(mx, __shfl_xor(mx, 8));
          float ea = __expf(a - mx), eb = __expf(b - mx);
          float ssum = ea + eb;
          ssum += __shfl_xor(ssum, 1);
          ssum += __shfl_xor(ssum, 2);
          ssum += __shfl_xor(ssum, 4);
          ssum += __shfl_xor(ssum, 8);
          float inv = 1.0f / ssum;
          const int h = hbase + hg;
          awc[(size_t)row * 128 + h * 16 + lrow] = ea * inv;
          awt[(size_t)row * 128 + h * 16 + lrow] = eb * inv;
        }
      }
    }
  }
}

// ---------------------------------------------------------------------------
extern "C" void kernel_launch(void* const* d_in, const int* in_sizes, int n_in,
                              void* d_out, int out_size, void* d_ws, size_t ws_size,
                              hipStream_t stream) {
  const float* Q    = (const float*)d_in[0];
  const float* Xf   = (const float*)d_in[1];
  const float* Wv   = (const float*)d_in[2];
  const float* bv   = (const float*)d_in[3];
  const float* Wso  = (const float*)d_in[4];
  const float* bso  = (const float*)d_in[5];
  const float* Waw  = (const float*)d_in[6];
  const float* baw  = (const float*)d_in[7];
  const float* Wtso = (const float*)d_in[8];
  const float* btso = (const float*)d_in[9];
  const float* Wtaw = (const float*)d_in[10];
  const float* btaw = (const float*)d_in[11];
  float* out = (float*)d_out;

  unsigned short* Wt = (unsigned short*)d_ws;               // 512 KB
  float* bcat = (float*)((char*)d_ws + 1024 * 256 * 2);     // 4 KB

  int M = in_sizes[0] / 256;  // 97920

  prep_weights<<<1024, 256, 0, stream>>>(Wv, bv, Wso, bso, Waw, baw,
                                         Wtso, btso, Wtaw, btaw, Wt, bcat);

  dim3 g(8, M / 128);  // remapped in-kernel for XCD L2 panel locality
  gemm_main<<<g, 256, 0, stream>>>(Q, Xf, Wt, bcat, out, M);
}